// Round 1
// baseline (5004.496 us; speedup 1.0000x reference)
//
#include <hip/hip_runtime.h>
#include <math.h>

#define BB 16
#define SS 96
#define WW 48
#define EE 300
#define HH 256
#define GG 1024   // 4H
#define DD 512    // 2H
#define NSEQ 1536 // B*S
#define KW 556    // E + H

__device__ __forceinline__ float sigf(float v){ return 1.0f/(1.0f+__expf(-v)); }

// ---------------- init ----------------
__global__ __launch_bounds__(256) void k_init_word(float* __restrict__ h, float* __restrict__ c, float* __restrict__ ma){
  int i = blockIdx.x*256 + threadIdx.x;   // grid covers 2*NSEQ*HH == NSEQ*DD == 786432
  h[i] = 0.f; c[i] = 0.f; ma[i] = -1e30f;
}

__global__ __launch_bounds__(256) void k_zero2(float* __restrict__ a, float* __restrict__ b){
  int i = blockIdx.x*256 + threadIdx.x;   // 2*BB*HH = 8192
  a[i] = 0.f; b[i] = 0.f;
}

// ---------------- word-level fused step GEMM ----------------
// gates[dir][m][n] = bias[n] + sum_k<300 x[m,t,k]*Wih[n,k] + sum_k<256 h[dir][m][k]*Uhh[n,k]
// grid (24, 16, 2), block 256
__global__ __launch_bounds__(256) void k_word_gates(
    const float* __restrict__ x,
    const float* __restrict__ Wf, const float* __restrict__ Uf, const float* __restrict__ bf,
    const float* __restrict__ Wb, const float* __restrict__ Ub, const float* __restrict__ bb,
    const float* __restrict__ hw, float* __restrict__ gates, int step)
{
  __shared__ float As[16][64];
  __shared__ float Bs[16][64];
  const int dir = blockIdx.z;
  const int t   = dir ? (WW-1-step) : step;
  const float* __restrict__ Wih  = dir ? Wb : Wf;
  const float* __restrict__ Uhh  = dir ? Ub : Uf;
  const float* __restrict__ bias = dir ? bb : bf;
  const float* __restrict__ h    = hw + (size_t)dir*NSEQ*HH;
  float* __restrict__ gout       = gates + (size_t)dir*NSEQ*GG;

  const int tid = threadIdx.x;
  const int m0 = blockIdx.x*64, n0 = blockIdx.y*64;
  const int lr = tid & 63;          // row within tile (lanes contiguous -> conflict-free LDS writes)
  const int lk = (tid >> 6) << 2;   // k offset 0/4/8/12 per wave
  const int tx = tid & 15, ty = tid >> 4;

  const float* xrow = x + ((size_t)(m0+lr)*WW + t)*EE;
  const float* hrow = h + (size_t)(m0+lr)*HH;
  const float* wrow = Wih + (size_t)(n0+lr)*EE;
  const float* urow = Uhh + (size_t)(n0+lr)*HH;

  float acc[4][4];
  #pragma unroll
  for (int i=0;i<4;i++)
    #pragma unroll
    for (int j=0;j<4;j++) acc[i][j] = 0.f;

  for (int K0 = 0; K0 < KW; K0 += 16){
    int k = K0 + lk;
    float4 av = {0.f,0.f,0.f,0.f}, bv = {0.f,0.f,0.f,0.f};
    if (k < KW){  // KW%4==0 and EE%4==0 -> groups never straddle
      av = (k < EE) ? *(const float4*)(xrow + k) : *(const float4*)(hrow + (k-EE));
      bv = (k < EE) ? *(const float4*)(wrow + k) : *(const float4*)(urow + (k-EE));
    }
    __syncthreads();
    As[lk+0][lr]=av.x; As[lk+1][lr]=av.y; As[lk+2][lr]=av.z; As[lk+3][lr]=av.w;
    Bs[lk+0][lr]=bv.x; Bs[lk+1][lr]=bv.y; Bs[lk+2][lr]=bv.z; Bs[lk+3][lr]=bv.w;
    __syncthreads();
    #pragma unroll
    for (int kk=0; kk<16; kk++){
      float4 a  = *(const float4*)(&As[kk][ty*4]);
      float4 bq = *(const float4*)(&Bs[kk][tx*4]);
      float ar[4] = {a.x,a.y,a.z,a.w};
      float br[4] = {bq.x,bq.y,bq.z,bq.w};
      #pragma unroll
      for (int i=0;i<4;i++)
        #pragma unroll
        for (int j=0;j<4;j++) acc[i][j] += ar[i]*br[j];
    }
  }
  float4 b4 = *(const float4*)(bias + n0 + tx*4);
  #pragma unroll
  for (int i=0;i<4;i++){
    float* crow = gout + (size_t)(m0 + ty*4 + i)*GG + n0 + tx*4;
    float4 v = {acc[i][0]+b4.x, acc[i][1]+b4.y, acc[i][2]+b4.z, acc[i][3]+b4.w};
    *(float4*)crow = v;
  }
}

// ---------------- word-level cell + online masked max-pool ----------------
__global__ __launch_bounds__(256) void k_word_cell(
    const float* __restrict__ gates, float* __restrict__ hw, float* __restrict__ cw,
    float* __restrict__ maxacc, const int* __restrict__ slen, int step)
{
  int i = blockIdx.x*256 + threadIdx.x;       // 2*NSEQ*HH
  int dir = i / (NSEQ*HH);
  int r = i % (NSEQ*HH);
  int m = r / HH, j = r % HH;
  const float* g = gates + (size_t)dir*NSEQ*GG + (size_t)m*GG;
  float gi = g[j], gf = g[HH+j], gg = g[2*HH+j], go = g[3*HH+j];
  float c = cw[i];
  float cn = sigf(gf)*c + sigf(gi)*tanhf(gg);
  float hn = sigf(go)*tanhf(cn);
  cw[i] = cn; hw[i] = hn;
  int t = dir ? (WW-1-step) : step;
  if (t < slen[m]){
    float* ma = maxacc + (size_t)m*DD + dir*HH + j;
    *ma = fmaxf(*ma, hn);
  }
}

__global__ __launch_bounds__(256) void k_pool_mask(
    const float* __restrict__ maxacc, float* __restrict__ pooled, const int* __restrict__ dl)
{
  int i = blockIdx.x*256 + threadIdx.x;       // NSEQ*DD
  int m = i / DD; int b = m / SS; int s = m % SS;
  pooled[i] = (s < dl[b]) ? maxacc[i] : 0.f;
}

// ---------------- generic GEMM: C[1536xGG] = A[1536xK] @ B[GGxK]^T + bias ----------------
// grid (24,16,2): z picks direction
__global__ __launch_bounds__(256) void k_gemm_bias(
    const float* __restrict__ A,
    const float* __restrict__ B0, const float* __restrict__ B1,
    const float* __restrict__ bias0, const float* __restrict__ bias1,
    float* __restrict__ C0, float* __restrict__ C1, int K)
{
  __shared__ float As[16][64];
  __shared__ float Bs[16][64];
  const int z = blockIdx.z;
  const float* __restrict__ Bw = z ? B1 : B0;
  const float* __restrict__ bias = z ? bias1 : bias0;
  float* __restrict__ C = z ? C1 : C0;

  const int tid = threadIdx.x;
  const int m0 = blockIdx.x*64, n0 = blockIdx.y*64;
  const int lr = tid & 63;
  const int lk = (tid >> 6) << 2;
  const int tx = tid & 15, ty = tid >> 4;

  const float* arow = A  + (size_t)(m0+lr)*K;
  const float* brow = Bw + (size_t)(n0+lr)*K;

  float acc[4][4];
  #pragma unroll
  for (int i=0;i<4;i++)
    #pragma unroll
    for (int j=0;j<4;j++) acc[i][j] = 0.f;

  for (int K0 = 0; K0 < K; K0 += 16){
    float4 av = *(const float4*)(arow + K0 + lk);
    float4 bv = *(const float4*)(brow + K0 + lk);
    __syncthreads();
    As[lk+0][lr]=av.x; As[lk+1][lr]=av.y; As[lk+2][lr]=av.z; As[lk+3][lr]=av.w;
    Bs[lk+0][lr]=bv.x; Bs[lk+1][lr]=bv.y; Bs[lk+2][lr]=bv.z; Bs[lk+3][lr]=bv.w;
    __syncthreads();
    #pragma unroll
    for (int kk=0; kk<16; kk++){
      float4 a  = *(const float4*)(&As[kk][ty*4]);
      float4 bq = *(const float4*)(&Bs[kk][tx*4]);
      float ar[4] = {a.x,a.y,a.z,a.w};
      float br[4] = {bq.x,bq.y,bq.z,bq.w};
      #pragma unroll
      for (int i=0;i<4;i++)
        #pragma unroll
        for (int j=0;j<4;j++) acc[i][j] += ar[i]*br[j];
    }
  }
  float4 b4 = *(const float4*)(bias + n0 + tx*4);
  #pragma unroll
  for (int i=0;i<4;i++){
    float* crow = C + (size_t)(m0 + ty*4 + i)*GG + n0 + tx*4;
    float4 v = {acc[i][0]+b4.x, acc[i][1]+b4.y, acc[i][2]+b4.z, acc[i][3]+b4.w};
    *(float4*)crow = v;
  }
}

// ---------------- sentence-level recurrent gates: gates[dir][b][n] = Gx[dir][b*SS+t][n] + h[b] . U[n] ----------------
// grid (64, 2), block 256
__global__ __launch_bounds__(256) void k_sent_gates(
    const float* __restrict__ Gx,
    const float* __restrict__ U0, const float* __restrict__ U1,
    const float* __restrict__ hst, float* __restrict__ gates, int step)
{
  const int dir = blockIdx.y;
  const float* __restrict__ U = dir ? U1 : U0;
  const float* __restrict__ h = hst + dir*BB*HH;
  const int t = dir ? (SS-1-step) : step;
  __shared__ float hsh[BB*(HH+4)];
  const int tid = threadIdx.x;
  for (int i4 = tid; i4 < BB*HH/4; i4 += 256){
    int bi = (i4<<2) >> 8;         // /HH
    int k  = (i4<<2) & (HH-1);
    *(float4*)(hsh + bi*(HH+4) + k) = ((const float4*)h)[i4];
  }
  __syncthreads();
  const int bi = tid & 15;
  const int nn = tid >> 4;
  const int n  = blockIdx.x*16 + nn;
  const float* Ur = U + (size_t)n*HH;
  const float* hb = hsh + bi*(HH+4);
  float acc = 0.f;
  #pragma unroll 8
  for (int k=0;k<HH;k+=4){
    float4 u  = *(const float4*)(Ur+k);
    float4 hv = *(const float4*)(hb+k);
    acc += u.x*hv.x + u.y*hv.y + u.z*hv.z + u.w*hv.w;
  }
  gates[(size_t)dir*BB*GG + bi*GG + n] =
      acc + Gx[(size_t)dir*NSEQ*GG + ((size_t)bi*SS + t)*GG + n];
}

// cell for sentence LSTMs; writes output sequence (optionally doc-length masked)
__global__ __launch_bounds__(256) void k_sent_cell(
    const float* __restrict__ gates, float* __restrict__ hst, float* __restrict__ cst,
    float* __restrict__ outseq, const int* __restrict__ dl, int step, int mask_out)
{
  int i = blockIdx.x*256 + threadIdx.x;  // 2*BB*HH = 8192
  int dir = i / (BB*HH);
  int r = i % (BB*HH);
  int b = r / HH, j = r % HH;
  const float* g = gates + (size_t)dir*BB*GG + (size_t)b*GG;
  float gi = g[j], gf = g[HH+j], gg = g[2*HH+j], go = g[3*HH+j];
  float c = cst[i];
  float cn = sigf(gf)*c + sigf(gi)*tanhf(gg);
  float hn = sigf(go)*tanhf(cn);
  cst[i] = cn; hst[i] = hn;
  int t = dir ? (SS-1-step) : step;
  float ho = hn;
  if (mask_out && t >= dl[b]) ho = 0.f;
  outseq[((size_t)b*SS + t)*DD + dir*HH + j] = ho;
}

// ---------------- restricted attention ----------------
// block per (b,s); hr[b,s] = [X[b,s], ctx]
__global__ __launch_bounds__(256) void k_attn(
    const float* __restrict__ X, const float* __restrict__ aw_,
    const float* __restrict__ ab_, const int* __restrict__ dl, float* __restrict__ hr)
{
  const int bs = blockIdx.x, b = bs / SS, s = bs % SS, tid = threadIdx.x;
  const float* xc = X + (size_t)bs*DD;
  float* outp = hr + (size_t)bs*(2*DD);
  for (int d=tid; d<DD; d+=256) outp[d] = xc[d];
  const int dlb = dl[b];
  if (s >= dlb){
    for (int d=tid; d<DD; d+=256) outp[DD+d] = 0.f;
    return;
  }
  __shared__ float xw[7][DD];
  __shared__ float red4[4][23];
  __shared__ float redm[23];
  for (int k=0;k<7;k++){
    int idx = s-3+k; idx = idx < 0 ? 0 : (idx > SS-1 ? SS-1 : idx);
    const float* row = X + ((size_t)b*SS + idx)*DD;
    for (int d=tid; d<DD; d+=256) xw[k][d] = row[d];
  }
  __syncthreads();
  float pv[23];
  #pragma unroll
  for (int i=0;i<23;i++) pv[i] = 0.f;
  #pragma unroll
  for (int pass=0; pass<2; pass++){
    int d = tid + pass*256;
    float xv = xc[d];
    pv[0] += xv*xv;
    pv[1] += xv * aw_[DD + d];
    float w1 = aw_[d];
    #pragma unroll
    for (int k=0;k<7;k++){
      float wv = xw[k][d];
      pv[2+3*k] += wv*xv;
      pv[3+3*k] += wv*wv;
      pv[4+3*k] += wv*w1;
    }
  }
  const int lane = tid & 63, wid = tid >> 6;
  #pragma unroll
  for (int i=0;i<23;i++){
    float v = pv[i];
    for (int o=32;o>0;o>>=1) v += __shfl_down(v, o, 64);
    if (lane==0) red4[wid][i] = v;
  }
  __syncthreads();
  if (tid < 23) redm[tid] = red4[0][tid]+red4[1][tid]+red4[2][tid]+red4[3][tid];
  __syncthreads();
  float nc = fmaxf(sqrtf(redm[0]), 1e-12f);
  float cterm = redm[1] + ab_[0];
  float wsim = aw_[2*DD];
  float sck[7]; float mx = -1e30f;
  #pragma unroll
  for (int k=0;k<7;k++){
    int idx = s-3+k;
    bool valid = (idx >= 0) && (idx < dlb);
    float nw = fmaxf(sqrtf(redm[3+3*k]), 1e-12f);
    float sim = sigf(redm[2+3*k] / (nw*nc));
    float sc = redm[4+3*k] + cterm + sim*wsim;
    sck[k] = valid ? sc : -1e30f;
    mx = fmaxf(mx, sck[k]);
  }
  float sum = 0.f;
  #pragma unroll
  for (int k=0;k<7;k++){ sck[k] = __expf(sck[k]-mx); sum += sck[k]; }
  float inv = 1.0f/sum;
  for (int d=tid; d<DD; d+=256){
    float cv = 0.f;
    #pragma unroll
    for (int k=0;k<7;k++) cv += sck[k]*xw[k][d];
    outp[DD+d] = cv*inv;
  }
}

// ---------------- classifier + softmax ----------------
__global__ __launch_bounds__(256) void k_cls(
    const float* __restrict__ h2, const float* __restrict__ Wc,
    const float* __restrict__ bc, float* __restrict__ out)
{
  int pos = blockIdx.x*4 + (threadIdx.x >> 6);   // 1536 positions, wave per position
  int lane = threadIdx.x & 63;
  const float* hv = h2 + (size_t)pos*DD;
  float a0 = 0.f, a1 = 0.f;
  for (int d=lane; d<DD; d+=64){ float h = hv[d]; a0 += h*Wc[d]; a1 += h*Wc[DD+d]; }
  for (int o=32;o>0;o>>=1){ a0 += __shfl_down(a0,o,64); a1 += __shfl_down(a1,o,64); }
  if (lane==0){
    float l0 = a0 + bc[0], l1 = a1 + bc[1];
    float m = fmaxf(l0,l1);
    float e0 = __expf(l0-m), e1 = __expf(l1-m);
    float s = e0+e1;
    out[pos*2]   = e0/s;
    out[pos*2+1] = e1/s;
  }
}

extern "C" void kernel_launch(void* const* d_in, const int* in_sizes, int n_in,
                              void* d_out, int out_size, void* d_ws, size_t ws_size,
                              hipStream_t stream) {
  const float* x    = (const float*)d_in[0];
  const int* slen   = (const int*)d_in[1];
  const int* dl     = (const int*)d_in[2];
  const float* wl_Wf=(const float*)d_in[3];
  const float* wl_Uf=(const float*)d_in[4];
  const float* wl_bf=(const float*)d_in[5];
  const float* wl_Wb=(const float*)d_in[6];
  const float* wl_Ub=(const float*)d_in[7];
  const float* wl_bb=(const float*)d_in[8];
  const float* sl_Wf=(const float*)d_in[9];
  const float* sl_Uf=(const float*)d_in[10];
  const float* sl_bf=(const float*)d_in[11];
  const float* sl_Wb=(const float*)d_in[12];
  const float* sl_Ub=(const float*)d_in[13];
  const float* sl_bb=(const float*)d_in[14];
  const float* attw =(const float*)d_in[15];
  const float* attb =(const float*)d_in[16];
  const float* m2_Wf=(const float*)d_in[17];
  const float* m2_Uf=(const float*)d_in[18];
  const float* m2_bf=(const float*)d_in[19];
  const float* m2_Wb=(const float*)d_in[20];
  const float* m2_Ub=(const float*)d_in[21];
  const float* m2_bb=(const float*)d_in[22];
  const float* clsW =(const float*)d_in[23];
  const float* clsb =(const float*)d_in[24];
  float* out = (float*)d_out;

  float* p = (float*)d_ws;
  float* h_w    = p; p += 2*NSEQ*HH;
  float* c_w    = p; p += 2*NSEQ*HH;
  float* gates_w= p; p += 2*(size_t)NSEQ*GG;
  float* maxacc = p; p += NSEQ*DD;
  float* pooled = p; p += NSEQ*DD;
  float* Gx1    = p; p += 2*(size_t)NSEQ*GG;
  float* h_s    = p; p += 2*BB*HH;
  float* c_s    = p; p += 2*BB*HH;
  float* gates_s= p; p += 2*BB*GG;
  float* hs     = p; p += NSEQ*DD;
  float* hr     = p; p += (size_t)NSEQ*2*DD;
  float* Gx2    = p; p += 2*(size_t)NSEQ*GG;
  float* h2     = p; p += NSEQ*DD;

  // word-level BiLSTM + online max-pool
  k_init_word<<<3072,256,0,stream>>>(h_w, c_w, maxacc);
  for (int s=0; s<WW; s++){
    k_word_gates<<<dim3(24,16,2),256,0,stream>>>(x, wl_Wf, wl_Uf, wl_bf, wl_Wb, wl_Ub, wl_bb, h_w, gates_w, s);
    k_word_cell<<<3072,256,0,stream>>>(gates_w, h_w, c_w, maxacc, slen, s);
  }
  k_pool_mask<<<3072,256,0,stream>>>(maxacc, pooled, dl);

  // sentence LSTM 1
  k_gemm_bias<<<dim3(24,16,2),256,0,stream>>>(pooled, sl_Wf, sl_Wb, sl_bf, sl_bb, Gx1, Gx1+(size_t)NSEQ*GG, DD);
  k_zero2<<<32,256,0,stream>>>(h_s, c_s);
  for (int t=0; t<SS; t++){
    k_sent_gates<<<dim3(64,2),256,0,stream>>>(Gx1, sl_Uf, sl_Ub, h_s, gates_s, t);
    k_sent_cell<<<32,256,0,stream>>>(gates_s, h_s, c_s, hs, dl, t, 1);
  }

  // restricted attention
  k_attn<<<1536,256,0,stream>>>(hs, attw, attb, dl, hr);

  // sentence LSTM 2
  k_gemm_bias<<<dim3(24,16,2),256,0,stream>>>(hr, m2_Wf, m2_Wb, m2_bf, m2_bb, Gx2, Gx2+(size_t)NSEQ*GG, 2*DD);
  k_zero2<<<32,256,0,stream>>>(h_s, c_s);
  for (int t=0; t<SS; t++){
    k_sent_gates<<<dim3(64,2),256,0,stream>>>(Gx2, m2_Uf, m2_Ub, h_s, gates_s, t);
    k_sent_cell<<<32,256,0,stream>>>(gates_s, h_s, c_s, h2, dl, t, 0);
  }

  // classifier
  k_cls<<<384,256,0,stream>>>(h2, clsW, clsb, out);
}

// Round 2
// 4176.665 us; speedup vs baseline: 1.1982x; 1.1982x over previous
//
#include <hip/hip_runtime.h>
#include <math.h>

#define BB 16
#define SS 96
#define WW 48
#define EE 300
#define HH 256
#define GG 1024   // 4H
#define DD 512    // 2H
#define NSEQ 1536 // B*S
#define KXP 320   // E padded to mult of 32

typedef __attribute__((ext_vector_type(8))) short bf16x8;
typedef __attribute__((ext_vector_type(4))) float f32x4;

__device__ __forceinline__ float sigf(float v){ return 1.0f/(1.0f+__expf(-v)); }

__device__ __forceinline__ unsigned short f2bf(float f){
  union { float f; unsigned u; } v; v.f = f;
  unsigned u = v.u;
  u += 0x7FFFu + ((u>>16)&1u);   // RNE
  return (unsigned short)(u>>16);
}

// ---------------- conversions ----------------
__global__ __launch_bounds__(256) void k_cvt_x(const float* __restrict__ x, unsigned short* __restrict__ xb){
  int i = blockIdx.x*256 + threadIdx.x;        // 73728*320
  int row = i / KXP, k = i % KXP;
  xb[i] = (k < EE) ? f2bf(x[(size_t)row*EE + k]) : 0;
}
__global__ __launch_bounds__(256) void k_cvt_W(const float* __restrict__ Wf, const float* __restrict__ Wb_,
                                               unsigned short* __restrict__ Wb){
  int i = blockIdx.x*256 + threadIdx.x;        // 2*1024*320
  int dir = i / (GG*KXP);
  int rem = i % (GG*KXP);
  int n = rem / KXP, k = rem % KXP;
  const float* src = dir ? Wb_ : Wf;
  Wb[i] = (k < EE) ? f2bf(src[(size_t)n*EE + k]) : 0;
}
__global__ __launch_bounds__(256) void k_cvt_U(const float* __restrict__ Uf, const float* __restrict__ Ub_,
                                               unsigned short* __restrict__ Ub){
  int i = blockIdx.x*256 + threadIdx.x;        // 2*1024*256
  int dir = i / (GG*HH);
  int rem = i % (GG*HH);
  Ub[i] = f2bf((dir ? Ub_ : Uf)[rem]);
}

// ---------------- init ----------------
__global__ __launch_bounds__(256) void k_init_word(unsigned short* __restrict__ hb, float* __restrict__ c, float* __restrict__ ma){
  int i = blockIdx.x*256 + threadIdx.x;   // 786432
  hb[i] = 0; c[i] = 0.f; ma[i] = -1e30f;
}
__global__ __launch_bounds__(256) void k_zero2(float* __restrict__ a, float* __restrict__ b){
  int i = blockIdx.x*256 + threadIdx.x;   // 8192
  a[i] = 0.f; b[i] = 0.f;
}

// ---------------- word-level fused MFMA step: gates GEMM + cell + maxpool ----------------
// grid (96, 4, 2): m-block(16 rows), j-block(64 of H), dir. block 256 = 4 waves, wave = gate.
__global__ __launch_bounds__(256) void k_wstep(
    const unsigned short* __restrict__ xb,   // [73728][320] bf16
    const unsigned short* __restrict__ Wb,   // [2][1024][320] bf16
    const unsigned short* __restrict__ Ub,   // [2][1024][256] bf16
    const float* __restrict__ bf_, const float* __restrict__ bb_,
    unsigned short* __restrict__ hb,         // [2][1536][256] bf16
    float* __restrict__ cw,                  // [2][1536][256]
    float* __restrict__ maxacc,              // [1536][512]
    const int* __restrict__ slen, int step)
{
  const int dir = blockIdx.z;
  const int t = dir ? (WW-1-step) : step;
  const int m0 = blockIdx.x*16;
  const int j0 = blockIdx.y*64;
  const int tid = threadIdx.x;
  const int g = tid >> 6;          // wave index = gate
  const int lane = tid & 63;
  const int lm = lane & 15;
  const int lk8 = (lane >> 4) * 8;

  const unsigned short* arow_x = xb + ((size_t)(m0+lm)*WW + t)*KXP + lk8;
  const unsigned short* arow_h = hb + ((size_t)dir*NSEQ + (m0+lm))*HH + lk8;
  const unsigned short* WbD = Wb + (size_t)dir*GG*KXP;
  const unsigned short* UbD = Ub + (size_t)dir*GG*HH;

  f32x4 acc[4];
  #pragma unroll
  for (int nt=0;nt<4;nt++){ acc[nt][0]=0.f; acc[nt][1]=0.f; acc[nt][2]=0.f; acc[nt][3]=0.f; }

  const unsigned short* brw[4]; const unsigned short* bru[4];
  #pragma unroll
  for (int nt=0;nt<4;nt++){
    int n = g*HH + j0 + nt*16 + lm;
    brw[nt] = WbD + (size_t)n*KXP + lk8;
    bru[nt] = UbD + (size_t)n*HH + lk8;
  }
  #pragma unroll
  for (int kc=0;kc<10;kc++){
    bf16x8 a = *(const bf16x8*)(arow_x + kc*32);
    #pragma unroll
    for (int nt=0;nt<4;nt++){
      bf16x8 b = *(const bf16x8*)(brw[nt] + kc*32);
      acc[nt] = __builtin_amdgcn_mfma_f32_16x16x32_bf16(a, b, acc[nt], 0, 0, 0);
    }
  }
  #pragma unroll
  for (int kc=0;kc<8;kc++){
    bf16x8 a = *(const bf16x8*)(arow_h + kc*32);
    #pragma unroll
    for (int nt=0;nt<4;nt++){
      bf16x8 b = *(const bf16x8*)(bru[nt] + kc*32);
      acc[nt] = __builtin_amdgcn_mfma_f32_16x16x32_bf16(a, b, acc[nt], 0, 0, 0);
    }
  }

  __shared__ float gbuf[4][16][64];
  #pragma unroll
  for (int nt=0;nt<4;nt++)
    #pragma unroll
    for (int r=0;r<4;r++)
      gbuf[g][(lane>>4)*4 + r][nt*16 + lm] = acc[nt][r];
  __syncthreads();

  // cell + maxpool: thread -> (mm, 4 consecutive j)
  const int mm = tid >> 4;
  const int jj = (tid & 15) * 4;
  const int m  = m0 + mm;
  f32x4 iv = *(const f32x4*)&gbuf[0][mm][jj];
  f32x4 fv = *(const f32x4*)&gbuf[1][mm][jj];
  f32x4 gv = *(const f32x4*)&gbuf[2][mm][jj];
  f32x4 ov = *(const f32x4*)&gbuf[3][mm][jj];
  const float* bias = dir ? bb_ : bf_;
  const size_t ci = ((size_t)dir*NSEQ + m)*HH + j0 + jj;
  f32x4 cv = *(const f32x4*)(cw + ci);
  const bool upd = t < slen[m];
  float* map = maxacc + (size_t)m*DD + dir*HH + j0 + jj;
  f32x4 mv = *(const f32x4*)map;
  union { unsigned short s[4]; unsigned long long u; } pk;
  #pragma unroll
  for (int q=0;q<4;q++){
    int j = j0 + jj + q;
    float i_ = iv[q] + bias[j];
    float f_ = fv[q] + bias[HH + j];
    float g_ = gv[q] + bias[2*HH + j];
    float o_ = ov[q] + bias[3*HH + j];
    float cn = sigf(f_)*cv[q] + sigf(i_)*tanhf(g_);
    float hn = sigf(o_)*tanhf(cn);
    cv[q] = cn;
    pk.s[q] = f2bf(hn);
    mv[q] = fmaxf(mv[q], hn);
  }
  *(f32x4*)(cw + ci) = cv;
  if (upd) *(f32x4*)map = mv;
  *(unsigned long long*)(hb + ci) = pk.u;
}

__global__ __launch_bounds__(256) void k_pool_mask(
    const float* __restrict__ maxacc, float* __restrict__ pooled, const int* __restrict__ dl)
{
  int i = blockIdx.x*256 + threadIdx.x;       // NSEQ*DD
  int m = i / DD; int b = m / SS; int s = m % SS;
  pooled[i] = (s < dl[b]) ? maxacc[i] : 0.f;
}

// ---------------- fp32 GEMM: C[1536xGG] = A[1536xK] @ B[GGxK]^T + bias ----------------
__global__ __launch_bounds__(256) void k_gemm_bias(
    const float* __restrict__ A,
    const float* __restrict__ B0, const float* __restrict__ B1,
    const float* __restrict__ bias0, const float* __restrict__ bias1,
    float* __restrict__ C0, float* __restrict__ C1, int K)
{
  __shared__ float As[16][64];
  __shared__ float Bs[16][64];
  const int z = blockIdx.z;
  const float* __restrict__ Bw = z ? B1 : B0;
  const float* __restrict__ bias = z ? bias1 : bias0;
  float* __restrict__ C = z ? C1 : C0;

  const int tid = threadIdx.x;
  const int m0 = blockIdx.x*64, n0 = blockIdx.y*64;
  const int lr = tid & 63;
  const int lk = (tid >> 6) << 2;
  const int tx = tid & 15, ty = tid >> 4;

  const float* arow = A  + (size_t)(m0+lr)*K;
  const float* brow = Bw + (size_t)(n0+lr)*K;

  float acc[4][4];
  #pragma unroll
  for (int i=0;i<4;i++)
    #pragma unroll
    for (int j=0;j<4;j++) acc[i][j] = 0.f;

  for (int K0 = 0; K0 < K; K0 += 16){
    float4 av = *(const float4*)(arow + K0 + lk);
    float4 bv = *(const float4*)(brow + K0 + lk);
    __syncthreads();
    As[lk+0][lr]=av.x; As[lk+1][lr]=av.y; As[lk+2][lr]=av.z; As[lk+3][lr]=av.w;
    Bs[lk+0][lr]=bv.x; Bs[lk+1][lr]=bv.y; Bs[lk+2][lr]=bv.z; Bs[lk+3][lr]=bv.w;
    __syncthreads();
    #pragma unroll
    for (int kk=0; kk<16; kk++){
      float4 a  = *(const float4*)(&As[kk][ty*4]);
      float4 bq = *(const float4*)(&Bs[kk][tx*4]);
      float ar[4] = {a.x,a.y,a.z,a.w};
      float br[4] = {bq.x,bq.y,bq.z,bq.w};
      #pragma unroll
      for (int i=0;i<4;i++)
        #pragma unroll
        for (int j=0;j<4;j++) acc[i][j] += ar[i]*br[j];
    }
  }
  float4 b4 = *(const float4*)(bias + n0 + tx*4);
  #pragma unroll
  for (int i=0;i<4;i++){
    float* crow = C + (size_t)(m0 + ty*4 + i)*GG + n0 + tx*4;
    float4 v = {acc[i][0]+b4.x, acc[i][1]+b4.y, acc[i][2]+b4.z, acc[i][3]+b4.w};
    *(float4*)crow = v;
  }
}

// ---------------- sentence-level fused step: gates + cell + output ----------------
// grid (64, 2): j-block(4 of H), dir. block 256: wave = gate, p = b*4 + (j&3).
__global__ __launch_bounds__(256) void k_sstep(
    const float* __restrict__ Gx,   // [2][1536][1024] (bias included)
    const float* __restrict__ U0, const float* __restrict__ U1,  // [1024][256]
    float* __restrict__ h_s, float* __restrict__ c_s,  // [2][16][256]
    float* __restrict__ outseq,     // [16][96][512]
    const int* __restrict__ dl, int step, int mask_out)
{
  const int dir = blockIdx.y;
  const int t = dir ? (SS-1-step) : step;
  const int j0 = blockIdx.x*4;
  const int tid = threadIdx.x;
  __shared__ float h_sh[BB*260];
  __shared__ float gb[4][64];
  const float* hsrc = h_s + dir*BB*HH;
  for (int i = tid; i < BB*HH/4; i += 256){
    int b = i >> 6, kq = (i & 63) * 4;
    *(f32x4*)(h_sh + b*260 + kq) = *(const f32x4*)(hsrc + b*HH + kq);
  }
  __syncthreads();
  const int g = tid >> 6, p = tid & 63, b = p >> 2, j = j0 + (p & 3);
  const float* U = dir ? U1 : U0;
  const float* Ur = U + (size_t)(g*HH + j)*HH;
  const float* hh = h_sh + b*260;
  float a0=0.f, a1=0.f, a2=0.f, a3=0.f;
  #pragma unroll 4
  for (int k=0;k<HH;k+=16){
    f32x4 u0 = *(const f32x4*)(Ur+k);    f32x4 h0 = *(const f32x4*)(hh+k);
    f32x4 u1 = *(const f32x4*)(Ur+k+4);  f32x4 h1 = *(const f32x4*)(hh+k+4);
    f32x4 u2 = *(const f32x4*)(Ur+k+8);  f32x4 h2 = *(const f32x4*)(hh+k+8);
    f32x4 u3 = *(const f32x4*)(Ur+k+12); f32x4 h3 = *(const f32x4*)(hh+k+12);
    a0 += u0[0]*h0[0]+u0[1]*h0[1]+u0[2]*h0[2]+u0[3]*h0[3];
    a1 += u1[0]*h1[0]+u1[1]*h1[1]+u1[2]*h1[2]+u1[3]*h1[3];
    a2 += u2[0]*h2[0]+u2[1]*h2[1]+u2[2]*h2[2]+u2[3]*h2[3];
    a3 += u3[0]*h3[0]+u3[1]*h3[1]+u3[2]*h3[2]+u3[3]*h3[3];
  }
  gb[g][p] = (a0+a1)+(a2+a3) + Gx[(size_t)dir*NSEQ*GG + ((size_t)b*SS + t)*GG + g*HH + j];
  __syncthreads();
  if (tid < 64){
    const int pp = tid, b2 = pp >> 2, j2 = j0 + (pp & 3);
    float i_=gb[0][pp], f_=gb[1][pp], g_=gb[2][pp], o_=gb[3][pp];
    const size_t ci = (size_t)(dir*BB + b2)*HH + j2;
    float cn = sigf(f_)*c_s[ci] + sigf(i_)*tanhf(g_);
    float hn = sigf(o_)*tanhf(cn);
    c_s[ci] = cn; h_s[ci] = hn;
    float ho = hn;
    if (mask_out && t >= dl[b2]) ho = 0.f;
    outseq[((size_t)b2*SS + t)*DD + dir*HH + j2] = ho;
  }
}

// ---------------- restricted attention ----------------
__global__ __launch_bounds__(256) void k_attn(
    const float* __restrict__ X, const float* __restrict__ aw_,
    const float* __restrict__ ab_, const int* __restrict__ dl, float* __restrict__ hr)
{
  const int bs = blockIdx.x, b = bs / SS, s = bs % SS, tid = threadIdx.x;
  const float* xc = X + (size_t)bs*DD;
  float* outp = hr + (size_t)bs*(2*DD);
  for (int d=tid; d<DD; d+=256) outp[d] = xc[d];
  const int dlb = dl[b];
  if (s >= dlb){
    for (int d=tid; d<DD; d+=256) outp[DD+d] = 0.f;
    return;
  }
  __shared__ float xw[7][DD];
  __shared__ float red4[4][23];
  __shared__ float redm[23];
  for (int k=0;k<7;k++){
    int idx = s-3+k; idx = idx < 0 ? 0 : (idx > SS-1 ? SS-1 : idx);
    const float* row = X + ((size_t)b*SS + idx)*DD;
    for (int d=tid; d<DD; d+=256) xw[k][d] = row[d];
  }
  __syncthreads();
  float pv[23];
  #pragma unroll
  for (int i=0;i<23;i++) pv[i] = 0.f;
  #pragma unroll
  for (int pass=0; pass<2; pass++){
    int d = tid + pass*256;
    float xv = xc[d];
    pv[0] += xv*xv;
    pv[1] += xv * aw_[DD + d];
    float w1 = aw_[d];
    #pragma unroll
    for (int k=0;k<7;k++){
      float wv = xw[k][d];
      pv[2+3*k] += wv*xv;
      pv[3+3*k] += wv*wv;
      pv[4+3*k] += wv*w1;
    }
  }
  const int lane = tid & 63, wid = tid >> 6;
  #pragma unroll
  for (int i=0;i<23;i++){
    float v = pv[i];
    for (int o=32;o>0;o>>=1) v += __shfl_down(v, o, 64);
    if (lane==0) red4[wid][i] = v;
  }
  __syncthreads();
  if (tid < 23) redm[tid] = red4[0][tid]+red4[1][tid]+red4[2][tid]+red4[3][tid];
  __syncthreads();
  float nc = fmaxf(sqrtf(redm[0]), 1e-12f);
  float cterm = redm[1] + ab_[0];
  float wsim = aw_[2*DD];
  float sck[7]; float mx = -1e30f;
  #pragma unroll
  for (int k=0;k<7;k++){
    int idx = s-3+k;
    bool valid = (idx >= 0) && (idx < dlb);
    float nw = fmaxf(sqrtf(redm[3+3*k]), 1e-12f);
    float sim = sigf(redm[2+3*k] / (nw*nc));
    float sc = redm[4+3*k] + cterm + sim*wsim;
    sck[k] = valid ? sc : -1e30f;
    mx = fmaxf(mx, sck[k]);
  }
  float sum = 0.f;
  #pragma unroll
  for (int k=0;k<7;k++){ sck[k] = __expf(sck[k]-mx); sum += sck[k]; }
  float inv = 1.0f/sum;
  for (int d=tid; d<DD; d+=256){
    float cv = 0.f;
    #pragma unroll
    for (int k=0;k<7;k++) cv += sck[k]*xw[k][d];
    outp[DD+d] = cv*inv;
  }
}

// ---------------- classifier + softmax ----------------
__global__ __launch_bounds__(256) void k_cls(
    const float* __restrict__ h2, const float* __restrict__ Wc,
    const float* __restrict__ bc, float* __restrict__ out)
{
  int pos = blockIdx.x*4 + (threadIdx.x >> 6);
  int lane = threadIdx.x & 63;
  const float* hv = h2 + (size_t)pos*DD;
  float a0 = 0.f, a1 = 0.f;
  for (int d=lane; d<DD; d+=64){ float h = hv[d]; a0 += h*Wc[d]; a1 += h*Wc[DD+d]; }
  for (int o=32;o>0;o>>=1){ a0 += __shfl_down(a0,o,64); a1 += __shfl_down(a1,o,64); }
  if (lane==0){
    float l0 = a0 + bc[0], l1 = a1 + bc[1];
    float m = fmaxf(l0,l1);
    float e0 = __expf(l0-m), e1 = __expf(l1-m);
    float s = e0+e1;
    out[pos*2]   = e0/s;
    out[pos*2+1] = e1/s;
  }
}

extern "C" void kernel_launch(void* const* d_in, const int* in_sizes, int n_in,
                              void* d_out, int out_size, void* d_ws, size_t ws_size,
                              hipStream_t stream) {
  const float* x    = (const float*)d_in[0];
  const int* slen   = (const int*)d_in[1];
  const int* dl     = (const int*)d_in[2];
  const float* wl_Wf=(const float*)d_in[3];
  const float* wl_Uf=(const float*)d_in[4];
  const float* wl_bf=(const float*)d_in[5];
  const float* wl_Wb=(const float*)d_in[6];
  const float* wl_Ub=(const float*)d_in[7];
  const float* wl_bb=(const float*)d_in[8];
  const float* sl_Wf=(const float*)d_in[9];
  const float* sl_Uf=(const float*)d_in[10];
  const float* sl_bf=(const float*)d_in[11];
  const float* sl_Wb=(const float*)d_in[12];
  const float* sl_Ub=(const float*)d_in[13];
  const float* sl_bb=(const float*)d_in[14];
  const float* attw =(const float*)d_in[15];
  const float* attb =(const float*)d_in[16];
  const float* m2_Wf=(const float*)d_in[17];
  const float* m2_Uf=(const float*)d_in[18];
  const float* m2_bf=(const float*)d_in[19];
  const float* m2_Wb=(const float*)d_in[20];
  const float* m2_Ub=(const float*)d_in[21];
  const float* m2_bb=(const float*)d_in[22];
  const float* clsW =(const float*)d_in[23];
  const float* clsb =(const float*)d_in[24];
  float* out = (float*)d_out;

  // ---- workspace layout (bytes) ----
  char* base = (char*)d_ws;
  // Region A: xb during word phase, then reused
  unsigned short* xb = (unsigned short*)base;                    // 73728*320*2 = 47,185,920
  float* Gx1 = (float*)base;                                     // 12,582,912  (after word phase)
  float* Gx2 = (float*)(base + 12582912);                        // 12,582,912
  float* hr  = (float*)(base + 25165824);                        //  6,291,456
  float* hs  = (float*)(base + 31457280);                        //  3,145,728
  float* h2  = (float*)(base + 34603008);                        //  3,145,728
  char* pB = base + 47185920;
  unsigned short* Wb = (unsigned short*)pB;        pB += 1310720;
  unsigned short* Ub = (unsigned short*)pB;        pB += 1048576;
  unsigned short* hb = (unsigned short*)pB;        pB += 1572864;
  float* c_w    = (float*)pB;                      pB += 3145728;
  float* maxacc = (float*)pB;                      pB += 3145728;
  float* pooled = (float*)pB;                      pB += 3145728;
  float* h_s    = (float*)pB;                      pB += 32768;
  float* c_s    = (float*)pB;                      pB += 32768;

  // ---- conversions ----
  k_cvt_x<<<(73728*KXP)/256, 256, 0, stream>>>(x, xb);
  k_cvt_W<<<(2*GG*KXP)/256, 256, 0, stream>>>(wl_Wf, wl_Wb, Wb);
  k_cvt_U<<<(2*GG*HH)/256, 256, 0, stream>>>(wl_Uf, wl_Ub, Ub);

  // ---- word-level BiLSTM (MFMA fused steps) + online max-pool ----
  k_init_word<<<3072, 256, 0, stream>>>(hb, c_w, maxacc);
  for (int s=0; s<WW; s++){
    k_wstep<<<dim3(96,4,2), 256, 0, stream>>>(xb, Wb, Ub, wl_bf, wl_bb, hb, c_w, maxacc, slen, s);
  }
  k_pool_mask<<<3072, 256, 0, stream>>>(maxacc, pooled, dl);

  // ---- sentence LSTM 1 ----
  k_gemm_bias<<<dim3(24,16,2), 256, 0, stream>>>(pooled, sl_Wf, sl_Wb, sl_bf, sl_bb, Gx1, Gx1+(size_t)NSEQ*GG, DD);
  k_zero2<<<32, 256, 0, stream>>>(h_s, c_s);
  for (int t=0; t<SS; t++){
    k_sstep<<<dim3(64,2), 256, 0, stream>>>(Gx1, sl_Uf, sl_Ub, h_s, c_s, hs, dl, t, 1);
  }

  // ---- restricted attention ----
  k_attn<<<NSEQ, 256, 0, stream>>>(hs, attw, attb, dl, hr);

  // ---- sentence LSTM 2 ----
  k_gemm_bias<<<dim3(24,16,2), 256, 0, stream>>>(hr, m2_Wf, m2_Wb, m2_bf, m2_bb, Gx2, Gx2+(size_t)NSEQ*GG, 2*DD);
  k_zero2<<<32, 256, 0, stream>>>(h_s, c_s);
  for (int t=0; t<SS; t++){
    k_sstep<<<dim3(64,2), 256, 0, stream>>>(Gx2, m2_Uf, m2_Ub, h_s, c_s, h2, dl, t, 0);
  }

  // ---- classifier ----
  k_cls<<<NSEQ/4, 256, 0, stream>>>(h2, clsW, clsb, out);
}